// Round 1
// baseline (184.338 us; speedup 1.0000x reference)
//
#include <hip/hip_runtime.h>
#include <hip/hip_bf16.h>

#define N_ROWS 4096
#define D_FULL 1024
#define DHALF  512

typedef __attribute__((ext_vector_type(8))) short bf16x8;
typedef __attribute__((ext_vector_type(4))) float f32x4;

__device__ __forceinline__ unsigned short f2b(float f) {
  __hip_bfloat16 h = __float2bfloat16(f);
  union { __hip_bfloat16 b; unsigned short u; } cv;
  cv.b = h;
  return cv.u;
}

// ---------------- f32 -> bf16 (RNE), vectorized ----------------
__global__ __launch_bounds__(256) void k_cvt(const float* __restrict__ in,
                                             unsigned short* __restrict__ out,
                                             int n4) {
  int idx = blockIdx.x * 256 + threadIdx.x;
  if (idx < n4) {
    float4 v = reinterpret_cast<const float4*>(in)[idx];
    ushort4 o;
    o.x = f2b(v.x); o.y = f2b(v.y); o.z = f2b(v.z); o.w = f2b(v.w);
    reinterpret_cast<ushort4*>(out)[idx] = o;
  }
}

// ---------------- Gram: G_h[i][j] = sum_n x[n][h*512+i] * x[n][h*512+j] ----------------
// Output bf16, 2 heads contiguous (h*512*512).
__global__ __launch_bounds__(256) void k_gram(const unsigned short* __restrict__ xb,
                                              unsigned short* __restrict__ G) {
  const int h    = blockIdx.z;
  const int j0   = blockIdx.x * 64;
  const int i0   = blockIdx.y * 64;
  const int hoff = h * DHALF;

  __shared__ __align__(16) unsigned short ldsA[64][32];  // ldsA[i][k] = x[k0+k][hoff+i0+i]
  __shared__ __align__(16) unsigned short ldsB[64][32];

  const int tid  = threadIdx.x;
  const int lane = tid & 63;
  const int wave = tid >> 6;
  const int wr = (wave >> 1) * 32;   // wave quadrant
  const int wc = (wave & 1) * 32;
  const int fr = lane & 15;          // fragment row/col
  const int kg = (lane >> 4) * 8;    // k-group

  const int sk = tid >> 3;           // staging: k row 0..31
  const int sc = (tid & 7) * 8;      // staging: col group

  f32x4 acc[2][2] = {};

  for (int k0 = 0; k0 < N_ROWS; k0 += 32) {
    const unsigned short* srcA = xb + (size_t)(k0 + sk) * D_FULL + hoff + i0 + sc;
    const unsigned short* srcB = xb + (size_t)(k0 + sk) * D_FULL + hoff + j0 + sc;
    ushort4 a0 = reinterpret_cast<const ushort4*>(srcA)[0];
    ushort4 a1 = reinterpret_cast<const ushort4*>(srcA)[1];
    ushort4 b0 = reinterpret_cast<const ushort4*>(srcB)[0];
    ushort4 b1 = reinterpret_cast<const ushort4*>(srcB)[1];
    __syncthreads();
    ldsA[sc+0][sk] = a0.x; ldsA[sc+1][sk] = a0.y; ldsA[sc+2][sk] = a0.z; ldsA[sc+3][sk] = a0.w;
    ldsA[sc+4][sk] = a1.x; ldsA[sc+5][sk] = a1.y; ldsA[sc+6][sk] = a1.z; ldsA[sc+7][sk] = a1.w;
    ldsB[sc+0][sk] = b0.x; ldsB[sc+1][sk] = b0.y; ldsB[sc+2][sk] = b0.z; ldsB[sc+3][sk] = b0.w;
    ldsB[sc+4][sk] = b1.x; ldsB[sc+5][sk] = b1.y; ldsB[sc+6][sk] = b1.z; ldsB[sc+7][sk] = b1.w;
    __syncthreads();
    bf16x8 af0 = *reinterpret_cast<const bf16x8*>(&ldsA[wr + fr][kg]);
    bf16x8 af1 = *reinterpret_cast<const bf16x8*>(&ldsA[wr + 16 + fr][kg]);
    bf16x8 bf0 = *reinterpret_cast<const bf16x8*>(&ldsB[wc + fr][kg]);
    bf16x8 bf1 = *reinterpret_cast<const bf16x8*>(&ldsB[wc + 16 + fr][kg]);
    acc[0][0] = __builtin_amdgcn_mfma_f32_16x16x32_bf16(af0, bf0, acc[0][0], 0, 0, 0);
    acc[0][1] = __builtin_amdgcn_mfma_f32_16x16x32_bf16(af0, bf1, acc[0][1], 0, 0, 0);
    acc[1][0] = __builtin_amdgcn_mfma_f32_16x16x32_bf16(af1, bf0, acc[1][0], 0, 0, 0);
    acc[1][1] = __builtin_amdgcn_mfma_f32_16x16x32_bf16(af1, bf1, acc[1][1], 0, 0, 0);
  }

  unsigned short* g = G + (size_t)h * DHALF * DHALF;
  #pragma unroll
  for (int m = 0; m < 2; ++m)
    #pragma unroll
    for (int n = 0; n < 2; ++n)
      #pragma unroll
      for (int r = 0; r < 4; ++r) {
        int row = i0 + wr + m * 16 + (lane >> 4) * 4 + r;
        int col = j0 + wc + n * 16 + fr;
        g[row * DHALF + col] = f2b(acc[m][n][r]);
      }
}

// ---------------- small 512x512x512 GEMM, C = op(A)*op(B), bf16 in/out ----------------
// A(m,k) = TA ? A[k][m] : A[m][k];  B(k,n) = TB ? B[n][k] : B[k][n]
template<bool TA, bool TB>
__global__ __launch_bounds__(256) void k_small(const unsigned short* __restrict__ A0,
                                               const unsigned short* __restrict__ A1,
                                               const unsigned short* __restrict__ B0,
                                               const unsigned short* __restrict__ B1,
                                               unsigned short* __restrict__ Cd0,
                                               unsigned short* __restrict__ Cd1) {
  const unsigned short* A = blockIdx.z ? A1 : A0;
  const unsigned short* B = blockIdx.z ? B1 : B0;
  unsigned short* Cd      = blockIdx.z ? Cd1 : Cd0;
  const int n0 = blockIdx.x * 64;
  const int m0 = blockIdx.y * 64;

  __shared__ __align__(16) unsigned short ldsA[64][32];  // ldsA[m][k]
  __shared__ __align__(16) unsigned short ldsB[64][32];  // ldsB[n][k]

  const int tid  = threadIdx.x;
  const int lane = tid & 63;
  const int wave = tid >> 6;
  const int wr = (wave >> 1) * 32;
  const int wc = (wave & 1) * 32;
  const int fr = lane & 15;
  const int kg = (lane >> 4) * 8;

  f32x4 acc[2][2] = {};

  for (int k0 = 0; k0 < DHALF; k0 += 32) {
    ushort4 va0, va1, vb0, vb1;
    if constexpr (!TA) {
      const int m = tid >> 2, k8 = (tid & 3) * 8;
      const unsigned short* p = A + (size_t)(m0 + m) * DHALF + k0 + k8;
      va0 = reinterpret_cast<const ushort4*>(p)[0];
      va1 = reinterpret_cast<const ushort4*>(p)[1];
    } else {
      const int k = tid >> 3, m8 = (tid & 7) * 8;
      const unsigned short* p = A + (size_t)(k0 + k) * DHALF + m0 + m8;
      va0 = reinterpret_cast<const ushort4*>(p)[0];
      va1 = reinterpret_cast<const ushort4*>(p)[1];
    }
    if constexpr (!TB) {
      const int k = tid >> 3, n8 = (tid & 7) * 8;
      const unsigned short* p = B + (size_t)(k0 + k) * DHALF + n0 + n8;
      vb0 = reinterpret_cast<const ushort4*>(p)[0];
      vb1 = reinterpret_cast<const ushort4*>(p)[1];
    } else {
      const int n = tid >> 2, k8 = (tid & 3) * 8;
      const unsigned short* p = B + (size_t)(n0 + n) * DHALF + k0 + k8;
      vb0 = reinterpret_cast<const ushort4*>(p)[0];
      vb1 = reinterpret_cast<const ushort4*>(p)[1];
    }
    __syncthreads();
    if constexpr (!TA) {
      const int m = tid >> 2, k8 = (tid & 3) * 8;
      *reinterpret_cast<ushort4*>(&ldsA[m][k8])     = va0;
      *reinterpret_cast<ushort4*>(&ldsA[m][k8 + 4]) = va1;
    } else {
      const int k = tid >> 3, m8 = (tid & 7) * 8;
      ldsA[m8+0][k] = va0.x; ldsA[m8+1][k] = va0.y; ldsA[m8+2][k] = va0.z; ldsA[m8+3][k] = va0.w;
      ldsA[m8+4][k] = va1.x; ldsA[m8+5][k] = va1.y; ldsA[m8+6][k] = va1.z; ldsA[m8+7][k] = va1.w;
    }
    if constexpr (!TB) {
      const int k = tid >> 3, n8 = (tid & 7) * 8;
      ldsB[n8+0][k] = vb0.x; ldsB[n8+1][k] = vb0.y; ldsB[n8+2][k] = vb0.z; ldsB[n8+3][k] = vb0.w;
      ldsB[n8+4][k] = vb1.x; ldsB[n8+5][k] = vb1.y; ldsB[n8+6][k] = vb1.z; ldsB[n8+7][k] = vb1.w;
    } else {
      const int n = tid >> 2, k8 = (tid & 3) * 8;
      *reinterpret_cast<ushort4*>(&ldsB[n][k8])     = vb0;
      *reinterpret_cast<ushort4*>(&ldsB[n][k8 + 4]) = vb1;
    }
    __syncthreads();
    bf16x8 af0 = *reinterpret_cast<const bf16x8*>(&ldsA[wr + fr][kg]);
    bf16x8 af1 = *reinterpret_cast<const bf16x8*>(&ldsA[wr + 16 + fr][kg]);
    bf16x8 bf0 = *reinterpret_cast<const bf16x8*>(&ldsB[wc + fr][kg]);
    bf16x8 bf1 = *reinterpret_cast<const bf16x8*>(&ldsB[wc + 16 + fr][kg]);
    acc[0][0] = __builtin_amdgcn_mfma_f32_16x16x32_bf16(af0, bf0, acc[0][0], 0, 0, 0);
    acc[0][1] = __builtin_amdgcn_mfma_f32_16x16x32_bf16(af0, bf1, acc[0][1], 0, 0, 0);
    acc[1][0] = __builtin_amdgcn_mfma_f32_16x16x32_bf16(af1, bf0, acc[1][0], 0, 0, 0);
    acc[1][1] = __builtin_amdgcn_mfma_f32_16x16x32_bf16(af1, bf1, acc[1][1], 0, 0, 0);
  }

  #pragma unroll
  for (int m = 0; m < 2; ++m)
    #pragma unroll
    for (int n = 0; n < 2; ++n)
      #pragma unroll
      for (int r = 0; r < 4; ++r) {
        int row = m0 + wr + m * 16 + (lane >> 4) * 4 + r;
        int col = n0 + wc + n * 16 + fr;
        Cd[row * DHALF + col] = f2b(acc[m][n][r]);
      }
}

// ---------------- final: O[n][h*512+c] = sum_d x[n][h*512+d] * M_h[d][c], f32 out ----------------
__global__ __launch_bounds__(256) void k_final(const unsigned short* __restrict__ xb,
                                               const unsigned short* __restrict__ M0,
                                               const unsigned short* __restrict__ M1,
                                               float* __restrict__ out) {
  const int h = blockIdx.z;
  const unsigned short* M = h ? M1 : M0;
  const int c0   = blockIdx.x * 64;
  const int n0   = blockIdx.y * 64;
  const int hoff = h * DHALF;

  __shared__ __align__(16) unsigned short ldsA[64][32];  // ldsA[n][d] = x[n0+n][hoff+k0+d]
  __shared__ __align__(16) unsigned short ldsB[64][32];  // ldsB[c][d] = M[k0+d][c0+c]

  const int tid  = threadIdx.x;
  const int lane = tid & 63;
  const int wave = tid >> 6;
  const int wr = (wave >> 1) * 32;
  const int wc = (wave & 1) * 32;
  const int fr = lane & 15;
  const int kg = (lane >> 4) * 8;

  f32x4 acc[2][2] = {};

  for (int k0 = 0; k0 < DHALF; k0 += 32) {
    const int ai = tid >> 2, ak = (tid & 3) * 8;
    const unsigned short* pa = xb + (size_t)(n0 + ai) * D_FULL + hoff + k0 + ak;
    ushort4 va0 = reinterpret_cast<const ushort4*>(pa)[0];
    ushort4 va1 = reinterpret_cast<const ushort4*>(pa)[1];
    const int bk = tid >> 3, bc = (tid & 7) * 8;
    const unsigned short* pb = M + (size_t)(k0 + bk) * DHALF + c0 + bc;
    ushort4 vb0 = reinterpret_cast<const ushort4*>(pb)[0];
    ushort4 vb1 = reinterpret_cast<const ushort4*>(pb)[1];
    __syncthreads();
    *reinterpret_cast<ushort4*>(&ldsA[ai][ak])     = va0;
    *reinterpret_cast<ushort4*>(&ldsA[ai][ak + 4]) = va1;
    ldsB[bc+0][bk] = vb0.x; ldsB[bc+1][bk] = vb0.y; ldsB[bc+2][bk] = vb0.z; ldsB[bc+3][bk] = vb0.w;
    ldsB[bc+4][bk] = vb1.x; ldsB[bc+5][bk] = vb1.y; ldsB[bc+6][bk] = vb1.z; ldsB[bc+7][bk] = vb1.w;
    __syncthreads();
    bf16x8 af0 = *reinterpret_cast<const bf16x8*>(&ldsA[wr + fr][kg]);
    bf16x8 af1 = *reinterpret_cast<const bf16x8*>(&ldsA[wr + 16 + fr][kg]);
    bf16x8 bf0 = *reinterpret_cast<const bf16x8*>(&ldsB[wc + fr][kg]);
    bf16x8 bf1 = *reinterpret_cast<const bf16x8*>(&ldsB[wc + 16 + fr][kg]);
    acc[0][0] = __builtin_amdgcn_mfma_f32_16x16x32_bf16(af0, bf0, acc[0][0], 0, 0, 0);
    acc[0][1] = __builtin_amdgcn_mfma_f32_16x16x32_bf16(af0, bf1, acc[0][1], 0, 0, 0);
    acc[1][0] = __builtin_amdgcn_mfma_f32_16x16x32_bf16(af1, bf0, acc[1][0], 0, 0, 0);
    acc[1][1] = __builtin_amdgcn_mfma_f32_16x16x32_bf16(af1, bf1, acc[1][1], 0, 0, 0);
  }

  #pragma unroll
  for (int m = 0; m < 2; ++m)
    #pragma unroll
    for (int n = 0; n < 2; ++n)
      #pragma unroll
      for (int r = 0; r < 4; ++r) {
        int row = n0 + wr + m * 16 + (lane >> 4) * 4 + r;
        int col = hoff + c0 + wc + n * 16 + fr;
        out[(size_t)row * D_FULL + col] = acc[m][n][r];
      }
}

extern "C" void kernel_launch(void* const* d_in, const int* in_sizes, int n_in,
                              void* d_out, int out_size, void* d_ws, size_t ws_size,
                              hipStream_t stream) {
  const float* x   = (const float*)d_in[0];
  const float* Wq1 = (const float*)d_in[1];
  const float* Wq2 = (const float*)d_in[2];
  const float* Wk1 = (const float*)d_in[3];
  const float* Wk2 = (const float*)d_in[4];
  const float* Wv1 = (const float*)d_in[5];
  const float* Wv2 = (const float*)d_in[6];
  float* out = (float*)d_out;

  // workspace layout (ushort elements); ~13.1 MB total
  unsigned short* ws   = (unsigned short*)d_ws;
  unsigned short* xb   = ws;                       // 4096*1024
  unsigned short* Wqb1 = ws + 4194304;
  unsigned short* Wqb2 = Wqb1 + 262144;
  unsigned short* Wkb1 = Wqb2 + 262144;
  unsigned short* Wkb2 = Wkb1 + 262144;
  unsigned short* Wvb1 = Wkb2 + 262144;
  unsigned short* Wvb2 = Wvb1 + 262144;
  unsigned short* G0   = Wvb2 + 262144;            // Gram head 0
  unsigned short* G1   = G0 + 262144;              // Gram head 1
  unsigned short* C1_0 = G1 + 262144;
  unsigned short* C1_1 = C1_0 + 262144;
  unsigned short* C2_0 = G0;                       // reuse (G dead after stage 1)
  unsigned short* C2_1 = G1;
  unsigned short* M0   = C1_0;                     // reuse (C1 dead after stage 2)
  unsigned short* M1   = C1_1;

  // bf16 conversions
  k_cvt<<<4096, 256, 0, stream>>>(x,   xb,   1048576);
  k_cvt<<<256,  256, 0, stream>>>(Wq1, Wqb1, 65536);
  k_cvt<<<256,  256, 0, stream>>>(Wq2, Wqb2, 65536);
  k_cvt<<<256,  256, 0, stream>>>(Wk1, Wkb1, 65536);
  k_cvt<<<256,  256, 0, stream>>>(Wk2, Wkb2, 65536);
  k_cvt<<<256,  256, 0, stream>>>(Wv1, Wvb1, 65536);
  k_cvt<<<256,  256, 0, stream>>>(Wv2, Wvb2, 65536);

  // G_h = X_h^T X_h
  k_gram<<<dim3(8, 8, 2), 256, 0, stream>>>(xb, G0);
  // C1 = Wk * G
  k_small<false, false><<<dim3(8, 8, 2), 256, 0, stream>>>(Wkb1, Wkb2, G0, G1, C1_0, C1_1);
  // C2 = C1 * Wv^T
  k_small<false, true ><<<dim3(8, 8, 2), 256, 0, stream>>>(C1_0, C1_1, Wvb1, Wvb2, C2_0, C2_1);
  // M = Wq^T * C2
  k_small<true,  false><<<dim3(8, 8, 2), 256, 0, stream>>>(Wqb1, Wqb2, C2_0, C2_1, M0, M1);
  // O[:, h*512 + c] = X_h * M_h
  k_final<<<dim3(8, 64, 2), 256, 0, stream>>>(xb, M0, M1, out);
}

// Round 2
// 91.453 us; speedup vs baseline: 2.0157x; 2.0157x over previous
//
#include <hip/hip_runtime.h>
#include <hip/hip_bf16.h>

#define N_ROWS 4096
#define D_FULL 1024
#define DHALF  512
#define SPLIT  8

typedef __attribute__((ext_vector_type(8))) short bf16x8;
typedef __attribute__((ext_vector_type(8))) unsigned short u16x8;
typedef __attribute__((ext_vector_type(4))) float f32x4;

__device__ __forceinline__ unsigned short f2b(float f) {
  __hip_bfloat16 h = __float2bfloat16(f);
  union { __hip_bfloat16 b; unsigned short u; } cv;
  cv.b = h;
  return cv.u;
}

// ---------------- x: f32 [4096][1024] -> xb bf16 [4096][1024] + xT bf16 [1024][4096] ----------------
__global__ __launch_bounds__(256) void k_cvtx(const float* __restrict__ x,
                                              unsigned short* __restrict__ xb,
                                              unsigned short* __restrict__ xT) {
  const int c0 = blockIdx.x * 64;
  const int n0 = blockIdx.y * 64;
  __shared__ unsigned short tile[64][66];   // pad 2 -> stride 132B, conflict-light column reads
  const int t  = threadIdx.x;
  const int r  = t >> 2;          // n-row within tile
  const int cq = (t & 3) * 16;    // col group

  unsigned short loc[16];
  #pragma unroll
  for (int i = 0; i < 4; ++i) {
    float4 v = *reinterpret_cast<const float4*>(&x[(size_t)(n0 + r) * D_FULL + c0 + cq + i * 4]);
    loc[i*4+0] = f2b(v.x); loc[i*4+1] = f2b(v.y); loc[i*4+2] = f2b(v.z); loc[i*4+3] = f2b(v.w);
  }
  // xb write (coalesced 16B x2)
  {
    u16x8 w0, w1;
    #pragma unroll
    for (int i = 0; i < 8; ++i) { w0[i] = loc[i]; w1[i] = loc[8+i]; }
    unsigned short* p = &xb[(size_t)(n0 + r) * D_FULL + c0 + cq];
    *reinterpret_cast<u16x8*>(p)     = w0;
    *reinterpret_cast<u16x8*>(p + 8) = w1;
  }
  // LDS write (4B ushort2)
  #pragma unroll
  for (int i = 0; i < 8; ++i) {
    ushort2 w; w.x = loc[2*i]; w.y = loc[2*i+1];
    *reinterpret_cast<ushort2*>(&tile[r][cq + 2*i]) = w;
  }
  __syncthreads();
  // xT write: thread handles xT row (c0 + t>>2), n-chunk (t&3)*16
  const int c  = t >> 2;
  const int ng = (t & 3) * 16;
  unsigned short o[16];
  #pragma unroll
  for (int i = 0; i < 16; ++i) o[i] = tile[ng + i][c];
  u16x8 w0, w1;
  #pragma unroll
  for (int i = 0; i < 8; ++i) { w0[i] = o[i]; w1[i] = o[8+i]; }
  unsigned short* p = &xT[(size_t)(c0 + c) * N_ROWS + n0 + ng];
  *reinterpret_cast<u16x8*>(p)     = w0;
  *reinterpret_cast<u16x8*>(p + 8) = w1;
}

// ---------------- 6 weights f32 -> bf16, one launch ----------------
__global__ __launch_bounds__(256) void k_cvtw(const float* __restrict__ w0, const float* __restrict__ w1,
                                              const float* __restrict__ w2, const float* __restrict__ w3,
                                              const float* __restrict__ w4, const float* __restrict__ w5,
                                              unsigned short* __restrict__ out) {
  const float* w;
  switch (blockIdx.y) {
    case 0: w = w0; break; case 1: w = w1; break; case 2: w = w2; break;
    case 3: w = w3; break; case 4: w = w4; break; default: w = w5; break;
  }
  int idx = blockIdx.x * 256 + threadIdx.x;   // < 65536
  float4 v = reinterpret_cast<const float4*>(w)[idx];
  ushort4 o;
  o.x = f2b(v.x); o.y = f2b(v.y); o.z = f2b(v.z); o.w = f2b(v.w);
  reinterpret_cast<ushort4*>(out + (size_t)blockIdx.y * (DHALF * DHALF))[idx] = o;
}

// ---------------- Gram split-K: Gp[z][i][j] = sum_{n in chunk s} xT[hoff+i][n]*xT[hoff+j][n] ----------------
__global__ __launch_bounds__(256) void k_gram(const unsigned short* __restrict__ xT,
                                              float* __restrict__ Gp) {
  const int z = blockIdx.z;              // h*SPLIT + s
  const int h = z >> 3, s = z & 7;
  const int j0 = blockIdx.x * 64;
  const int i0 = blockIdx.y * 64;

  __shared__ __align__(16) unsigned short ldsA[64][96];   // stride 192B: rows alternate bank halves
  __shared__ __align__(16) unsigned short ldsB[64][96];

  const int tid  = threadIdx.x;
  const int lane = tid & 63;
  const int wave = tid >> 6;
  const int wr = (wave >> 1) * 32;
  const int wc = (wave & 1) * 32;
  const int fr = lane & 15;
  const int kg = (lane >> 4) * 8;

  const int srow = tid >> 2;             // staging row 0..63
  const int scb  = (tid & 3) * 8;        // staging col base (ushorts); 2nd slot at +32

  const unsigned short* pA = xT + (size_t)(h * DHALF + i0 + srow) * N_ROWS + s * 512 + scb;
  const unsigned short* pB = xT + (size_t)(h * DHALF + j0 + srow) * N_ROWS + s * 512 + scb;

  f32x4 acc[2][2] = {};

  for (int it = 0; it < 8; ++it) {       // 8 x BK=64 = 512-chunk
    u16x8 a0 = *reinterpret_cast<const u16x8*>(pA);
    u16x8 a1 = *reinterpret_cast<const u16x8*>(pA + 32);
    u16x8 b0 = *reinterpret_cast<const u16x8*>(pB);
    u16x8 b1 = *reinterpret_cast<const u16x8*>(pB + 32);
    pA += 64; pB += 64;
    __syncthreads();
    *reinterpret_cast<u16x8*>(&ldsA[srow][scb])      = a0;
    *reinterpret_cast<u16x8*>(&ldsA[srow][scb + 32]) = a1;
    *reinterpret_cast<u16x8*>(&ldsB[srow][scb])      = b0;
    *reinterpret_cast<u16x8*>(&ldsB[srow][scb + 32]) = b1;
    __syncthreads();
    #pragma unroll
    for (int ks = 0; ks < 2; ++ks) {
      bf16x8 af0 = *reinterpret_cast<const bf16x8*>(&ldsA[wr + fr][ks*32 + kg]);
      bf16x8 af1 = *reinterpret_cast<const bf16x8*>(&ldsA[wr + 16 + fr][ks*32 + kg]);
      bf16x8 bf0 = *reinterpret_cast<const bf16x8*>(&ldsB[wc + fr][ks*32 + kg]);
      bf16x8 bf1 = *reinterpret_cast<const bf16x8*>(&ldsB[wc + 16 + fr][ks*32 + kg]);
      acc[0][0] = __builtin_amdgcn_mfma_f32_16x16x32_bf16(af0, bf0, acc[0][0], 0, 0, 0);
      acc[0][1] = __builtin_amdgcn_mfma_f32_16x16x32_bf16(af0, bf1, acc[0][1], 0, 0, 0);
      acc[1][0] = __builtin_amdgcn_mfma_f32_16x16x32_bf16(af1, bf0, acc[1][0], 0, 0, 0);
      acc[1][1] = __builtin_amdgcn_mfma_f32_16x16x32_bf16(af1, bf1, acc[1][1], 0, 0, 0);
    }
  }

  float* gp = Gp + (size_t)z * (DHALF * DHALF);
  #pragma unroll
  for (int m = 0; m < 2; ++m)
    #pragma unroll
    for (int n = 0; n < 2; ++n)
      #pragma unroll
      for (int r = 0; r < 4; ++r) {
        int row = i0 + wr + m * 16 + (lane >> 4) * 4 + r;
        int col = j0 + wc + n * 16 + fr;
        gp[row * DHALF + col] = acc[m][n][r];
      }
}

// ---------------- reduce partials -> G bf16 [2][512][512] ----------------
__global__ __launch_bounds__(256) void k_gred(const float* __restrict__ Gp,
                                              unsigned short* __restrict__ G) {
  int gid = blockIdx.x * 256 + threadIdx.x;       // 0..131071
  size_t e = (size_t)gid * 4;
  int h = (int)(e >> 18);
  size_t base = e & ((1u << 18) - 1);
  float4 sum = {0.f, 0.f, 0.f, 0.f};
  #pragma unroll
  for (int s = 0; s < SPLIT; ++s) {
    float4 v = *reinterpret_cast<const float4*>(&Gp[(((size_t)(h * SPLIT + s)) << 18) + base]);
    sum.x += v.x; sum.y += v.y; sum.z += v.z; sum.w += v.w;
  }
  ushort4 o;
  o.x = f2b(sum.x); o.y = f2b(sum.y); o.z = f2b(sum.z); o.w = f2b(sum.w);
  *reinterpret_cast<ushort4*>(&G[e]) = o;
}

// ---------------- small 512x512x512 GEMM, C = op(A)*op(B), bf16 in/out ----------------
template<bool TA, bool TB>
__global__ __launch_bounds__(256) void k_small(const unsigned short* __restrict__ A0,
                                               const unsigned short* __restrict__ A1,
                                               const unsigned short* __restrict__ B0,
                                               const unsigned short* __restrict__ B1,
                                               unsigned short* __restrict__ Cd0,
                                               unsigned short* __restrict__ Cd1) {
  const unsigned short* A = blockIdx.z ? A1 : A0;
  const unsigned short* B = blockIdx.z ? B1 : B0;
  unsigned short* Cd      = blockIdx.z ? Cd1 : Cd0;
  const int n0 = blockIdx.x * 64;
  const int m0 = blockIdx.y * 64;

  __shared__ __align__(16) unsigned short ldsA[64][32];
  __shared__ __align__(16) unsigned short ldsB[64][32];

  const int tid  = threadIdx.x;
  const int lane = tid & 63;
  const int wave = tid >> 6;
  const int wr = (wave >> 1) * 32;
  const int wc = (wave & 1) * 32;
  const int fr = lane & 15;
  const int kg = (lane >> 4) * 8;

  f32x4 acc[2][2] = {};

  for (int k0 = 0; k0 < DHALF; k0 += 32) {
    ushort4 va0, va1, vb0, vb1;
    if constexpr (!TA) {
      const int m = tid >> 2, k8 = (tid & 3) * 8;
      const unsigned short* p = A + (size_t)(m0 + m) * DHALF + k0 + k8;
      va0 = reinterpret_cast<const ushort4*>(p)[0];
      va1 = reinterpret_cast<const ushort4*>(p)[1];
    } else {
      const int k = tid >> 3, m8 = (tid & 7) * 8;
      const unsigned short* p = A + (size_t)(k0 + k) * DHALF + m0 + m8;
      va0 = reinterpret_cast<const ushort4*>(p)[0];
      va1 = reinterpret_cast<const ushort4*>(p)[1];
    }
    if constexpr (!TB) {
      const int k = tid >> 3, n8 = (tid & 7) * 8;
      const unsigned short* p = B + (size_t)(k0 + k) * DHALF + n0 + n8;
      vb0 = reinterpret_cast<const ushort4*>(p)[0];
      vb1 = reinterpret_cast<const ushort4*>(p)[1];
    } else {
      const int n = tid >> 2, k8 = (tid & 3) * 8;
      const unsigned short* p = B + (size_t)(n0 + n) * DHALF + k0 + k8;
      vb0 = reinterpret_cast<const ushort4*>(p)[0];
      vb1 = reinterpret_cast<const ushort4*>(p)[1];
    }
    __syncthreads();
    if constexpr (!TA) {
      const int m = tid >> 2, k8 = (tid & 3) * 8;
      *reinterpret_cast<ushort4*>(&ldsA[m][k8])     = va0;
      *reinterpret_cast<ushort4*>(&ldsA[m][k8 + 4]) = va1;
    } else {
      const int k = tid >> 3, m8 = (tid & 7) * 8;
      ldsA[m8+0][k] = va0.x; ldsA[m8+1][k] = va0.y; ldsA[m8+2][k] = va0.z; ldsA[m8+3][k] = va0.w;
      ldsA[m8+4][k] = va1.x; ldsA[m8+5][k] = va1.y; ldsA[m8+6][k] = va1.z; ldsA[m8+7][k] = va1.w;
    }
    if constexpr (!TB) {
      const int k = tid >> 3, n8 = (tid & 7) * 8;
      ldsB[n8+0][k] = vb0.x; ldsB[n8+1][k] = vb0.y; ldsB[n8+2][k] = vb0.z; ldsB[n8+3][k] = vb0.w;
      ldsB[n8+4][k] = vb1.x; ldsB[n8+5][k] = vb1.y; ldsB[n8+6][k] = vb1.z; ldsB[n8+7][k] = vb1.w;
    } else {
      const int n = tid >> 2, k8 = (tid & 3) * 8;
      *reinterpret_cast<ushort4*>(&ldsB[n][k8])     = vb0;
      *reinterpret_cast<ushort4*>(&ldsB[n][k8 + 4]) = vb1;
    }
    __syncthreads();
    bf16x8 af0 = *reinterpret_cast<const bf16x8*>(&ldsA[wr + fr][kg]);
    bf16x8 af1 = *reinterpret_cast<const bf16x8*>(&ldsA[wr + 16 + fr][kg]);
    bf16x8 bf0 = *reinterpret_cast<const bf16x8*>(&ldsB[wc + fr][kg]);
    bf16x8 bf1 = *reinterpret_cast<const bf16x8*>(&ldsB[wc + 16 + fr][kg]);
    acc[0][0] = __builtin_amdgcn_mfma_f32_16x16x32_bf16(af0, bf0, acc[0][0], 0, 0, 0);
    acc[0][1] = __builtin_amdgcn_mfma_f32_16x16x32_bf16(af0, bf1, acc[0][1], 0, 0, 0);
    acc[1][0] = __builtin_amdgcn_mfma_f32_16x16x32_bf16(af1, bf0, acc[1][0], 0, 0, 0);
    acc[1][1] = __builtin_amdgcn_mfma_f32_16x16x32_bf16(af1, bf1, acc[1][1], 0, 0, 0);
  }

  #pragma unroll
  for (int m = 0; m < 2; ++m)
    #pragma unroll
    for (int n = 0; n < 2; ++n)
      #pragma unroll
      for (int r = 0; r < 4; ++r) {
        int row = m0 + wr + m * 16 + (lane >> 4) * 4 + r;
        int col = n0 + wc + n * 16 + fr;
        Cd[row * DHALF + col] = f2b(acc[m][n][r]);
      }
}

// ---------------- final: O[n][h*512+c] = sum_d xb[n][h*512+d] * M_h[d][c], f32 out ----------------
__global__ __launch_bounds__(256) void k_final(const unsigned short* __restrict__ xb,
                                               const unsigned short* __restrict__ M0,
                                               const unsigned short* __restrict__ M1,
                                               float* __restrict__ out) {
  const int h = blockIdx.z;
  const unsigned short* M = h ? M1 : M0;
  const int c0   = blockIdx.x * 64;
  const int n0   = blockIdx.y * 64;
  const int hoff = h * DHALF;

  __shared__ __align__(16) unsigned short ldsA[64][32];
  __shared__ __align__(16) unsigned short ldsB[64][32];

  const int tid  = threadIdx.x;
  const int lane = tid & 63;
  const int wave = tid >> 6;
  const int wr = (wave >> 1) * 32;
  const int wc = (wave & 1) * 32;
  const int fr = lane & 15;
  const int kg = (lane >> 4) * 8;

  f32x4 acc[2][2] = {};

  for (int k0 = 0; k0 < DHALF; k0 += 32) {
    const int ai = tid >> 2, ak = (tid & 3) * 8;
    const unsigned short* pa = xb + (size_t)(n0 + ai) * D_FULL + hoff + k0 + ak;
    ushort4 va0 = reinterpret_cast<const ushort4*>(pa)[0];
    ushort4 va1 = reinterpret_cast<const ushort4*>(pa)[1];
    const int bk = tid >> 3, bc = (tid & 7) * 8;
    const unsigned short* pb = M + (size_t)(k0 + bk) * DHALF + c0 + bc;
    ushort4 vb0 = reinterpret_cast<const ushort4*>(pb)[0];
    ushort4 vb1 = reinterpret_cast<const ushort4*>(pb)[1];
    __syncthreads();
    *reinterpret_cast<ushort4*>(&ldsA[ai][ak])     = va0;
    *reinterpret_cast<ushort4*>(&ldsA[ai][ak + 4]) = va1;
    ldsB[bc+0][bk] = vb0.x; ldsB[bc+1][bk] = vb0.y; ldsB[bc+2][bk] = vb0.z; ldsB[bc+3][bk] = vb0.w;
    ldsB[bc+4][bk] = vb1.x; ldsB[bc+5][bk] = vb1.y; ldsB[bc+6][bk] = vb1.z; ldsB[bc+7][bk] = vb1.w;
    __syncthreads();
    bf16x8 af0 = *reinterpret_cast<const bf16x8*>(&ldsA[wr + fr][kg]);
    bf16x8 af1 = *reinterpret_cast<const bf16x8*>(&ldsA[wr + 16 + fr][kg]);
    bf16x8 bf0 = *reinterpret_cast<const bf16x8*>(&ldsB[wc + fr][kg]);
    bf16x8 bf1 = *reinterpret_cast<const bf16x8*>(&ldsB[wc + 16 + fr][kg]);
    acc[0][0] = __builtin_amdgcn_mfma_f32_16x16x32_bf16(af0, bf0, acc[0][0], 0, 0, 0);
    acc[0][1] = __builtin_amdgcn_mfma_f32_16x16x32_bf16(af0, bf1, acc[0][1], 0, 0, 0);
    acc[1][0] = __builtin_amdgcn_mfma_f32_16x16x32_bf16(af1, bf0, acc[1][0], 0, 0, 0);
    acc[1][1] = __builtin_amdgcn_mfma_f32_16x16x32_bf16(af1, bf1, acc[1][1], 0, 0, 0);
  }

  #pragma unroll
  for (int m = 0; m < 2; ++m)
    #pragma unroll
    for (int n = 0; n < 2; ++n)
      #pragma unroll
      for (int r = 0; r < 4; ++r) {
        int row = n0 + wr + m * 16 + (lane >> 4) * 4 + r;
        int col = hoff + c0 + wc + n * 16 + fr;
        out[(size_t)row * D_FULL + col] = acc[m][n][r];
      }
}

extern "C" void kernel_launch(void* const* d_in, const int* in_sizes, int n_in,
                              void* d_out, int out_size, void* d_ws, size_t ws_size,
                              hipStream_t stream) {
  const float* x   = (const float*)d_in[0];
  const float* Wq1 = (const float*)d_in[1];
  const float* Wq2 = (const float*)d_in[2];
  const float* Wk1 = (const float*)d_in[3];
  const float* Wk2 = (const float*)d_in[4];
  const float* Wv1 = (const float*)d_in[5];
  const float* Wv2 = (const float*)d_in[6];
  float* out = (float*)d_out;

  // workspace layout (ushort elements):
  //   xb   [4096*1024]          @ 0
  //   xT   [1024*4096]          @ 4194304
  //   Wb   [6*512*512]          @ 8388608   (q1,q2,k1,k2,v1,v2)
  //   G    [2*512*512]          @ 9961472
  //   Gp   f32 [16*512*512]     @ 10485760  (20 MB offset, 16 MB size)
  //   C1/C2/M reuse Gp region after k_gred
  unsigned short* ws   = (unsigned short*)d_ws;
  unsigned short* xb   = ws;
  unsigned short* xT   = ws + 4194304;
  unsigned short* Wb   = ws + 8388608;
  unsigned short* Wqb1 = Wb;
  unsigned short* Wqb2 = Wb + 262144;
  unsigned short* Wkb1 = Wb + 524288;
  unsigned short* Wkb2 = Wb + 786432;
  unsigned short* Wvb1 = Wb + 1048576;
  unsigned short* Wvb2 = Wb + 1310720;
  unsigned short* G0   = ws + 9961472;
  unsigned short* G1   = G0 + 262144;
  float*          Gp   = (float*)(ws + 10485760);
  unsigned short* C1_0 = (unsigned short*)Gp;       // Gp dead after k_gred
  unsigned short* C1_1 = C1_0 + 262144;
  unsigned short* C2_0 = C1_0 + 524288;
  unsigned short* C2_1 = C1_0 + 786432;
  unsigned short* M0   = C1_0 + 1048576;
  unsigned short* M1   = C1_0 + 1310720;

  k_cvtx<<<dim3(16, 64), 256, 0, stream>>>(x, xb, xT);
  k_cvtw<<<dim3(256, 6), 256, 0, stream>>>(Wq1, Wq2, Wk1, Wk2, Wv1, Wv2, Wb);
  k_gram<<<dim3(8, 8, 2 * SPLIT), 256, 0, stream>>>(xT, Gp);
  k_gred<<<512, 256, 0, stream>>>(Gp, G0);
  // C1 = Wk * G
  k_small<false, false><<<dim3(8, 8, 2), 256, 0, stream>>>(Wkb1, Wkb2, G0, G1, C1_0, C1_1);
  // C2 = C1 * Wv^T
  k_small<false, true ><<<dim3(8, 8, 2), 256, 0, stream>>>(C1_0, C1_1, Wvb1, Wvb2, C2_0, C2_1);
  // M = Wq^T * C2
  k_small<true,  false><<<dim3(8, 8, 2), 256, 0, stream>>>(Wqb1, Wqb2, C2_0, C2_1, M0, M1);
  // O[:, h*512 + c] = X_h * M_h
  k_final<<<dim3(8, 64, 2), 256, 0, stream>>>(xb, M0, M1, out);
}

// Round 3
// 61.895 us; speedup vs baseline: 2.9782x; 1.4775x over previous
//
#include <hip/hip_runtime.h>
#include <hip/hip_bf16.h>

#define N_ROWS 4096
#define D_FULL 1024
#define DHALF  512
#define GSPLIT 16

typedef __attribute__((ext_vector_type(8))) short bf16x8;
typedef __attribute__((ext_vector_type(8))) unsigned short u16x8;
typedef __attribute__((ext_vector_type(4))) float f32x4;

__device__ __forceinline__ unsigned short f2b(float f) {
  __hip_bfloat16 h = __float2bfloat16(f);
  union { __hip_bfloat16 b; unsigned short u; } cv;
  cv.b = h;
  return cv.u;
}
__device__ __forceinline__ float b2f(unsigned short u) {
  union { unsigned int i; float f; } cv;
  cv.i = ((unsigned int)u) << 16;
  return cv.f;
}

// async global -> LDS, 16 B per lane (lane i lands at ldsbase + i*16)
__device__ __forceinline__ void load_lds16(const void* g, void* l) {
  __builtin_amdgcn_global_load_lds(
      (const __attribute__((address_space(1))) unsigned int*)g,
      (__attribute__((address_space(3))) unsigned int*)l, 16, 0, 0);
}

__device__ __forceinline__ void storeC(float* p, float v) { *p = v; }
__device__ __forceinline__ void storeC(unsigned short* p, float v) { *p = f2b(v); }

// ---------------- x: f32 [4096][1024] -> xb bf16 [4096][1024] + xT bf16 [1024][4096] ----------------
__global__ __launch_bounds__(256) void k_cvtx(const float* __restrict__ x,
                                              unsigned short* __restrict__ xb,
                                              unsigned short* __restrict__ xT) {
  const int c0 = blockIdx.x * 64;
  const int n0 = blockIdx.y * 64;
  __shared__ unsigned short tile[64][66];
  const int t  = threadIdx.x;
  const int r  = t >> 2;
  const int cq = (t & 3) * 16;

  unsigned short loc[16];
  #pragma unroll
  for (int i = 0; i < 4; ++i) {
    float4 v = *reinterpret_cast<const float4*>(&x[(size_t)(n0 + r) * D_FULL + c0 + cq + i * 4]);
    loc[i*4+0] = f2b(v.x); loc[i*4+1] = f2b(v.y); loc[i*4+2] = f2b(v.z); loc[i*4+3] = f2b(v.w);
  }
  {
    u16x8 w0, w1;
    #pragma unroll
    for (int i = 0; i < 8; ++i) { w0[i] = loc[i]; w1[i] = loc[8+i]; }
    unsigned short* p = &xb[(size_t)(n0 + r) * D_FULL + c0 + cq];
    *reinterpret_cast<u16x8*>(p)     = w0;
    *reinterpret_cast<u16x8*>(p + 8) = w1;
  }
  #pragma unroll
  for (int i = 0; i < 8; ++i) {
    ushort2 w; w.x = loc[2*i]; w.y = loc[2*i+1];
    *reinterpret_cast<ushort2*>(&tile[r][cq + 2*i]) = w;
  }
  __syncthreads();
  const int c  = t >> 2;
  const int ng = (t & 3) * 16;
  unsigned short o[16];
  #pragma unroll
  for (int i = 0; i < 16; ++i) o[i] = tile[ng + i][c];
  u16x8 w0, w1;
  #pragma unroll
  for (int i = 0; i < 8; ++i) { w0[i] = o[i]; w1[i] = o[8+i]; }
  unsigned short* p = &xT[(size_t)(c0 + c) * N_ROWS + n0 + ng];
  *reinterpret_cast<u16x8*>(p)     = w0;
  *reinterpret_cast<u16x8*>(p + 8) = w1;
}

// ---------------- 6 weights f32 [512][512] -> Wb bf16 + WbT bf16 (transposed) ----------------
__global__ __launch_bounds__(256) void k_cvtw2(const float* __restrict__ w0, const float* __restrict__ w1,
                                               const float* __restrict__ w2, const float* __restrict__ w3,
                                               const float* __restrict__ w4, const float* __restrict__ w5,
                                               unsigned short* __restrict__ Wb,
                                               unsigned short* __restrict__ WbT) {
  const float* w;
  switch (blockIdx.z) {
    case 0: w = w0; break; case 1: w = w1; break; case 2: w = w2; break;
    case 3: w = w3; break; case 4: w = w4; break; default: w = w5; break;
  }
  unsigned short* ob  = Wb  + (size_t)blockIdx.z * (DHALF * DHALF);
  unsigned short* obT = WbT + (size_t)blockIdx.z * (DHALF * DHALF);
  const int c0 = blockIdx.x * 64;
  const int n0 = blockIdx.y * 64;
  __shared__ unsigned short tile[64][66];
  const int t  = threadIdx.x;
  const int r  = t >> 2;
  const int cq = (t & 3) * 16;

  unsigned short loc[16];
  #pragma unroll
  for (int i = 0; i < 4; ++i) {
    float4 v = *reinterpret_cast<const float4*>(&w[(size_t)(n0 + r) * DHALF + c0 + cq + i * 4]);
    loc[i*4+0] = f2b(v.x); loc[i*4+1] = f2b(v.y); loc[i*4+2] = f2b(v.z); loc[i*4+3] = f2b(v.w);
  }
  {
    u16x8 a, b;
    #pragma unroll
    for (int i = 0; i < 8; ++i) { a[i] = loc[i]; b[i] = loc[8+i]; }
    unsigned short* p = &ob[(size_t)(n0 + r) * DHALF + c0 + cq];
    *reinterpret_cast<u16x8*>(p)     = a;
    *reinterpret_cast<u16x8*>(p + 8) = b;
  }
  #pragma unroll
  for (int i = 0; i < 8; ++i) {
    ushort2 wv; wv.x = loc[2*i]; wv.y = loc[2*i+1];
    *reinterpret_cast<ushort2*>(&tile[r][cq + 2*i]) = wv;
  }
  __syncthreads();
  const int c  = t >> 2;
  const int ng = (t & 3) * 16;
  unsigned short o[16];
  #pragma unroll
  for (int i = 0; i < 16; ++i) o[i] = tile[ng + i][c];
  u16x8 a, b;
  #pragma unroll
  for (int i = 0; i < 8; ++i) { a[i] = o[i]; b[i] = o[8+i]; }
  unsigned short* p = &obT[(size_t)(c0 + c) * DHALF + n0 + ng];
  *reinterpret_cast<u16x8*>(p)     = a;
  *reinterpret_cast<u16x8*>(p + 8) = b;
}

// ---------------- big GEMM: C[m][n] = sum_k A[m][k] * B[n][k]  (m97 structure) ----------------
// 128x128 tile, BK=32, 4 waves (2x2), global_load_lds staging, LDS dbuf.
// grid: (N/128, M/128, numH*nSplit); z -> h = z/nSplit, s = z%nSplit.
template<typename OutT>
__global__ __launch_bounds__(256) void k_big(const unsigned short* __restrict__ A,
                                             const unsigned short* __restrict__ B,
                                             OutT* __restrict__ C,
                                             int lda, int ldb, int ldc, int kLen, int nSplit,
                                             long long hA, long long sA,
                                             long long hB, long long sB,
                                             long long hC, long long sC) {
  const int z = blockIdx.z;
  const int h = z / nSplit, s = z % nSplit;
  const unsigned short* Ab = A + (size_t)h * hA + (size_t)s * sA;
  const unsigned short* Bb = B + (size_t)h * hB + (size_t)s * sB;
  OutT* Cb = C + (size_t)h * hC + (size_t)s * sC;
  const int n0 = blockIdx.x * 128;
  const int m0 = blockIdx.y * 128;

  __shared__ __align__(16) unsigned short lds[2][2][128 * 32];  // [dbuf][A/B], 32 KB

  const int tid  = threadIdx.x;
  const int lane = tid & 63;
  const int wave = tid >> 6;
  const int wm = (wave >> 1) * 64;
  const int wn = (wave & 1) * 64;
  const int fr = lane & 15;
  const int kg = (lane >> 4) * 8;

  // staging: each wave covers 32 rows of the 128-row tile (2 issues of 16 rows) per operand
  const int srow = wave * 32 + (lane >> 2);
  const int scol = (lane & 3) * 8;
  const unsigned short* gA0 = Ab + (size_t)(m0 + srow) * lda + scol;
  const unsigned short* gA1 = gA0 + (size_t)16 * lda;
  const unsigned short* gB0 = Bb + (size_t)(n0 + srow) * ldb + scol;
  const unsigned short* gB1 = gB0 + (size_t)16 * ldb;
  const int stOff = wave * 1024;  // ushort offset of this wave's 32-row region

  f32x4 acc[4][4] = {};

  auto STAGE = [&](int buf, int kofs) {
    load_lds16(gA0 + kofs, &lds[buf][0][stOff]);
    load_lds16(gA1 + kofs, &lds[buf][0][stOff + 512]);
    load_lds16(gB0 + kofs, &lds[buf][1][stOff]);
    load_lds16(gB1 + kofs, &lds[buf][1][stOff + 512]);
  };
  auto COMPUTE = [&](int buf) {
    const unsigned short* la = &lds[buf][0][0];
    const unsigned short* lb = &lds[buf][1][0];
    bf16x8 af[4], bf[4];
    #pragma unroll
    for (int f = 0; f < 4; ++f) {
      af[f] = *reinterpret_cast<const bf16x8*>(&la[(wm + f * 16 + fr) * 32 + kg]);
      bf[f] = *reinterpret_cast<const bf16x8*>(&lb[(wn + f * 16 + fr) * 32 + kg]);
    }
    #pragma unroll
    for (int fm = 0; fm < 4; ++fm)
      #pragma unroll
      for (int fn = 0; fn < 4; ++fn)
        acc[fm][fn] = __builtin_amdgcn_mfma_f32_16x16x32_bf16(af[fm], bf[fn], acc[fm][fn], 0, 0, 0);
  };

  const int nt = kLen >> 5;
  STAGE(0, 0);
  __syncthreads();
  for (int t = 0; t < nt - 1; ++t) {
    STAGE((t + 1) & 1, (t + 1) * 32);
    COMPUTE(t & 1);
    __syncthreads();
  }
  COMPUTE((nt - 1) & 1);

  #pragma unroll
  for (int fm = 0; fm < 4; ++fm)
    #pragma unroll
    for (int fn = 0; fn < 4; ++fn)
      #pragma unroll
      for (int r = 0; r < 4; ++r) {
        int row = m0 + wm + fm * 16 + (lane >> 4) * 4 + r;
        int col = n0 + wn + fn * 16 + fr;
        storeC(&Cb[(size_t)row * ldc + col], acc[fm][fn][r]);
      }
}

// ---------------- small GEMM 512^3: C[m][n] = sum_k A[m][k]*B[n][k], bf16 in/out ----------------
// 64x64 tile, BK=128 (4 panels of [64][32]), 4 waves (2x2), dbuf, global_load_lds.
__global__ __launch_bounds__(256) void k_s(const unsigned short* __restrict__ A,
                                           const unsigned short* __restrict__ B,
                                           unsigned short* __restrict__ C,
                                           long long hA, long long hB, long long hC) {
  const int h = blockIdx.z;
  const unsigned short* Ab = A + (size_t)h * hA;
  const unsigned short* Bb = B + (size_t)h * hB;
  unsigned short* Cb = C + (size_t)h * hC;
  const int n0 = blockIdx.x * 64;
  const int m0 = blockIdx.y * 64;

  __shared__ __align__(16) unsigned short lds[2][2][4][64 * 32];  // [dbuf][A/B][panel], 64 KB

  const int tid  = threadIdx.x;
  const int lane = tid & 63;
  const int wave = tid >> 6;
  const int wm = (wave >> 1) * 32;
  const int wn = (wave & 1) * 32;
  const int fr = lane & 15;
  const int kg = (lane >> 4) * 8;

  // staging: wave w stages panel w (k-sub [w*32, w*32+32)) for A and B, 4 issues of 16 rows each
  const int srow = lane >> 2;
  const int scol = (lane & 3) * 8;
  const unsigned short* gA = Ab + (size_t)(m0 + srow) * DHALF + wave * 32 + scol;
  const unsigned short* gB = Bb + (size_t)(n0 + srow) * DHALF + wave * 32 + scol;

  f32x4 acc[2][2] = {};

  auto STAGE = [&](int buf, int kofs) {
    #pragma unroll
    for (int j = 0; j < 4; ++j) {
      load_lds16(gA + kofs + j * 16 * DHALF, &lds[buf][0][wave][j * 512]);
      load_lds16(gB + kofs + j * 16 * DHALF, &lds[buf][1][wave][j * 512]);
    }
  };
  auto COMPUTE = [&](int buf) {
    #pragma unroll
    for (int p = 0; p < 4; ++p) {
      bf16x8 a0 = *reinterpret_cast<const bf16x8*>(&lds[buf][0][p][(wm + fr) * 32 + kg]);
      bf16x8 a1 = *reinterpret_cast<const bf16x8*>(&lds[buf][0][p][(wm + 16 + fr) * 32 + kg]);
      bf16x8 b0 = *reinterpret_cast<const bf16x8*>(&lds[buf][1][p][(wn + fr) * 32 + kg]);
      bf16x8 b1 = *reinterpret_cast<const bf16x8*>(&lds[buf][1][p][(wn + 16 + fr) * 32 + kg]);
      acc[0][0] = __builtin_amdgcn_mfma_f32_16x16x32_bf16(a0, b0, acc[0][0], 0, 0, 0);
      acc[0][1] = __builtin_amdgcn_mfma_f32_16x16x32_bf16(a0, b1, acc[0][1], 0, 0, 0);
      acc[1][0] = __builtin_amdgcn_mfma_f32_16x16x32_bf16(a1, b0, acc[1][0], 0, 0, 0);
      acc[1][1] = __builtin_amdgcn_mfma_f32_16x16x32_bf16(a1, b1, acc[1][1], 0, 0, 0);
    }
  };

  STAGE(0, 0);
  __syncthreads();
  for (int t = 0; t < 3; ++t) {
    STAGE((t + 1) & 1, (t + 1) * 128);
    COMPUTE(t & 1);
    __syncthreads();
  }
  COMPUTE(1);

  #pragma unroll
  for (int fm = 0; fm < 2; ++fm)
    #pragma unroll
    for (int fn = 0; fn < 2; ++fn)
      #pragma unroll
      for (int r = 0; r < 4; ++r) {
        int row = m0 + wm + fm * 16 + (lane >> 4) * 4 + r;
        int col = n0 + wn + fn * 16 + fr;
        Cb[(size_t)row * DHALF + col] = f2b(acc[fm][fn][r]);
      }
}

// ---------------- reduce bf16 partials -> G bf16 [2][512][512] ----------------
__global__ __launch_bounds__(256) void k_gred(const unsigned short* __restrict__ Gp,
                                              unsigned short* __restrict__ G) {
  int gid = blockIdx.x * 256 + threadIdx.x;   // 0..65535
  int h = gid >> 15;
  size_t e = (size_t)(gid & 32767) * 8;
  size_t base = (size_t)h * GSPLIT * (DHALF * DHALF) + e;
  float sum[8] = {};
  #pragma unroll
  for (int s = 0; s < GSPLIT; ++s) {
    u16x8 v = *reinterpret_cast<const u16x8*>(&Gp[base + (size_t)s * (DHALF * DHALF)]);
    #pragma unroll
    for (int i = 0; i < 8; ++i) sum[i] += b2f(v[i]);
  }
  u16x8 o;
  #pragma unroll
  for (int i = 0; i < 8; ++i) o[i] = f2b(sum[i]);
  *reinterpret_cast<u16x8*>(&G[(size_t)h * (DHALF * DHALF) + e]) = o;
}

extern "C" void kernel_launch(void* const* d_in, const int* in_sizes, int n_in,
                              void* d_out, int out_size, void* d_ws, size_t ws_size,
                              hipStream_t stream) {
  const float* x   = (const float*)d_in[0];
  const float* Wq1 = (const float*)d_in[1];
  const float* Wq2 = (const float*)d_in[2];
  const float* Wk1 = (const float*)d_in[3];
  const float* Wk2 = (const float*)d_in[4];
  const float* Wv1 = (const float*)d_in[5];
  const float* Wv2 = (const float*)d_in[6];
  float* out = (float*)d_out;

  // workspace layout (ushort elements), total ~44 MB
  unsigned short* ws  = (unsigned short*)d_ws;
  unsigned short* xb  = ws;                    // [4096][1024]
  unsigned short* xT  = ws + 4194304;          // [1024][4096]
  unsigned short* Wb  = ws + 8388608;          // 6x[512][512]: q1,q2,k1,k2,v1,v2
  unsigned short* WbT = ws + 9961472;          // transposes, same order
  unsigned short* G   = ws + 11534336;         // [2][512][512]
  unsigned short* P   = ws + 12058624;         // [2][512][512]  P = Wq^T Wk
  unsigned short* TT  = ws + 12582912;         // [2][512][512]  TT = (G Wv^T)^T
  unsigned short* MT  = ws + 13107200;         // [2][512][512]  MT = M^T
  unsigned short* Gp  = ws + 13631488;         // [2*GSPLIT][512][512] bf16 partials

  const long long HH = 262144;                 // 512*512

  k_cvtx<<<dim3(16, 64), 256, 0, stream>>>(x, xb, xT);
  k_cvtw2<<<dim3(8, 8, 6), 256, 0, stream>>>(Wq1, Wq2, Wk1, Wk2, Wv1, Wv2, Wb, WbT);

  // P = WqT * (WkT)^T   (P[i][j] = sum_d Wq[d][i] Wk[d][j])
  k_s<<<dim3(8, 8, 2), 256, 0, stream>>>(WbT, WbT + 2 * HH, P, HH, HH, HH);

  // Gram partials: Gp[h*16+s][i][j] = sum_{n in s-chunk} xT[h*512+i][n] * xT[h*512+j][n]
  k_big<unsigned short><<<dim3(4, 4, 2 * GSPLIT), 256, 0, stream>>>(
      xT, xT, Gp, N_ROWS, N_ROWS, DHALF, N_ROWS / GSPLIT, GSPLIT,
      (long long)DHALF * N_ROWS, N_ROWS / GSPLIT,
      (long long)DHALF * N_ROWS, N_ROWS / GSPLIT,
      GSPLIT * HH, HH);
  k_gred<<<256, 256, 0, stream>>>(Gp, G);

  // TT = Wv * G^T  (TT[j][i] = sum_k Wv[j][k] G[i][k] = T[i][j])
  k_s<<<dim3(8, 8, 2), 256, 0, stream>>>(Wb + 4 * HH, G, TT, HH, HH, HH);
  // MT = TT * P^T  (MT[j][i] = sum_k TT[j][k] P[i][k] = M[i][j])
  k_s<<<dim3(8, 8, 2), 256, 0, stream>>>(TT, P, MT, HH, HH, HH);

  // out[n][h*512+c] = sum_d xb[n][h*512+d] * MT[c][d]
  k_big<float><<<dim3(4, 32, 2), 256, 0, stream>>>(
      xb, MT, out, D_FULL, DHALF, D_FULL, DHALF, 1,
      (long long)DHALF, 0, HH, 0, (long long)DHALF, 0);
}